// Round 2
// baseline (768.019 us; speedup 1.0000x reference)
//
#include <hip/hip_runtime.h>
#include <hip/hip_bf16.h>

#define EMB 64
#define XCOLS 20
#define NSYMP 15

__global__ void zero_kernel(int* __restrict__ p, int n) {
    int i = blockIdx.x * blockDim.x + threadIdx.x;
    if (i < n) p[i] = 0;
}

// ---------------- embedding ----------------
__global__ void embed_kernel(const int* __restrict__ x,
                             const float* __restrict__ bt,
                             const float* __restrict__ gt,
                             const float* __restrict__ st,
                             float* __restrict__ h0, int N) {
    __shared__ int xs[4 * XCOLS];
    int node = blockIdx.x * 4 + (threadIdx.x >> 6);
    int d = threadIdx.x & 63;
    if (threadIdx.x < 4 * XCOLS) {
        int n2 = blockIdx.x * 4 + threadIdx.x / XCOLS;
        int c = threadIdx.x % XCOLS;
        xs[threadIdx.x] = (n2 < N) ? x[n2 * XCOLS + c] : 0;
    }
    __syncthreads();
    if (node >= N) return;
    const int* xr = &xs[(threadIdx.x >> 6) * XCOLS];
    int bi = xr[1] + 2 * xr[2] + 3 * xr[3];   // argmax of one-hot
    int g = xr[4];
    float f = 0.f;
#pragma unroll
    for (int j = 0; j < NSYMP; ++j) {
        int sj = xr[5 + j];
        f += st[(j * 3 + sj) * EMB + d];
    }
    float val = (bt[bi * EMB + d] + gt[g * EMB + d] + f * (1.f / 15.f)) * (1.f / 3.f);
    h0[node * EMB + d] = val;
}

// ---------------- dual GEMM: outL = h@Wl+bl, outR = h@Wr+br (64x64 weights) ----
__global__ void gemm_dual_kernel(const float* __restrict__ h,
                                 const float* __restrict__ Wl, const float* __restrict__ bl,
                                 const float* __restrict__ Wr, const float* __restrict__ br,
                                 float* __restrict__ outL, float* __restrict__ outR, int N) {
    __shared__ float wl[EMB * EMB];
    __shared__ float wr[EMB * EMB];
    __shared__ float hr[4 * EMB];
    for (int i = threadIdx.x; i < EMB * EMB; i += 256) {
        wl[i] = Wl[i];
        wr[i] = Wr[i];
    }
    __syncthreads();
    int ngroups = (N + 3) / 4;
    int r = threadIdx.x >> 6;
    int d = threadIdx.x & 63;
    for (int g = blockIdx.x; g < ngroups; g += gridDim.x) {
        int node = g * 4 + r;
        __syncthreads();
        if (node < N) hr[threadIdx.x] = h[(size_t)g * 4 * EMB + threadIdx.x];
        __syncthreads();
        if (node < N) {
            float al = bl[d], ar = br[d];
#pragma unroll
            for (int k = 0; k < EMB; ++k) {
                float hv = hr[r * EMB + k];
                al += hv * wl[k * EMB + d];
                ar += hv * wr[k * EMB + d];
            }
            outL[node * EMB + d] = al;
            outR[node * EMB + d] = ar;
        }
    }
}

// ---------------- CSR build (edge_index marshalled as int32!) ----------------
__global__ void hist_kernel(const int* __restrict__ ei, int* __restrict__ deg, int E) {
    for (int i = blockIdx.x * blockDim.x + threadIdx.x; i < E; i += gridDim.x * blockDim.x)
        atomicAdd(&deg[ei[E + i]], 1);
}

__global__ void scanA_kernel(const int* __restrict__ deg, int* __restrict__ tmp,
                             int* __restrict__ bsum, int N) {
    __shared__ int s[256];
    int t = threadIdx.x;
    int i = blockIdx.x * 256 + t;
    s[t] = (i < N) ? deg[i] : 0;
    __syncthreads();
    for (int off = 1; off < 256; off <<= 1) {
        int v = (t >= off) ? s[t - off] : 0;
        __syncthreads();
        s[t] += v;
        __syncthreads();
    }
    if (i < N) tmp[i] = s[t];
    if (t == 255) bsum[blockIdx.x] = s[255];
}

__global__ void scanB_kernel(int* __restrict__ bsum, int nb) {
    __shared__ int s[1024];
    int t = threadIdx.x;
    s[t] = (t < nb) ? bsum[t] : 0;
    __syncthreads();
    for (int off = 1; off < 1024; off <<= 1) {
        int v = (t >= off) ? s[t - off] : 0;
        __syncthreads();
        s[t] += v;
        __syncthreads();
    }
    if (t < nb) bsum[t] = s[t];
}

__global__ void scanC_kernel(const int* __restrict__ tmp, const int* __restrict__ bsum,
                             const int* __restrict__ deg, int* __restrict__ offs,
                             int* __restrict__ cursor, int N) {
    int i = blockIdx.x * 256 + threadIdx.x;
    if (i >= N) return;
    int base = (blockIdx.x > 0) ? bsum[blockIdx.x - 1] : 0;
    int incl = tmp[i] + base;
    offs[i + 1] = incl;
    cursor[i] = incl - deg[i];
    if (i == 0) offs[0] = 0;
}

__global__ void scatter_kernel(const int* __restrict__ ei, int* __restrict__ cursor,
                               int* __restrict__ ssrc, int E) {
    for (int i = blockIdx.x * blockDim.x + threadIdx.x; i < E; i += gridDim.x * blockDim.x) {
        int dst = ei[E + i];
        int src = ei[i];
        int p = atomicAdd(&cursor[dst], 1);
        ssrc[p] = src;
    }
}

// ---------------- GATv2 layer, one wave per destination node ----------------
template <int L>
__global__ void gat_kernel(const float* __restrict__ xl, const float* __restrict__ xr,
                           const int* __restrict__ offs, const int* __restrict__ ssrc,
                           const float* __restrict__ att, const float* __restrict__ bias,
                           const float* __restrict__ linW, const float* __restrict__ linb,
                           float* __restrict__ out, int N) {
    int wid = blockIdx.x * 4 + (threadIdx.x >> 6);
    int lane = threadIdx.x & 63;
    if (wid >= N) return;

    float att_l = att[lane];
    float xr_l = xr[wid * EMB + lane];
    float bias_l = bias[lane];
    int e0 = offs[wid];
    int e1 = offs[wid + 1];

    float m = -1e30f, s = 0.f, acc = 0.f;
    for (int e = e0; e <= e1; ++e) {             // e==e1 is the self-loop
        int src = (e < e1) ? ssrc[e] : wid;
        float xls = xl[src * EMB + lane];
        float t = xls + xr_l;
        t = (t > 0.f) ? t : 0.2f * t;            // leaky_relu(0.2)
        float v = att_l * t;
        // reduce logit within head group
        v += __shfl_xor(v, 1);
        v += __shfl_xor(v, 2);
        v += __shfl_xor(v, 4);
        v += __shfl_xor(v, 8);
        if (L == 2) {
            v += __shfl_xor(v, 16);
            v += __shfl_xor(v, 32);
        }
        float nm = fmaxf(m, v);
        float sc = __expf(m - nm);
        float p = __expf(v - nm);
        s = s * sc + p;
        acc = acc * sc + p * xls;
        m = nm;
    }
    float val = acc / (s + 1e-16f) + bias_l;
    if (L == 1) {
        out[wid * EMB + lane] = (val > 0.f) ? val : (__expf(val) - 1.f);
    } else {
        float r = val * linW[lane];
        r += __shfl_xor(r, 1);
        r += __shfl_xor(r, 2);
        r += __shfl_xor(r, 4);
        r += __shfl_xor(r, 8);
        r += __shfl_xor(r, 16);
        r += __shfl_xor(r, 32);
        if (lane == 0) out[wid] = r + linb[0];
    }
}

extern "C" void kernel_launch(void* const* d_in, const int* in_sizes, int n_in,
                              void* d_out, int out_size, void* d_ws, size_t ws_size,
                              hipStream_t stream) {
    const int* x = (const int*)d_in[0];
    const int* ei = (const int*)d_in[1];          // int32 marshalled
    const float* birth_tab = (const float*)d_in[2];
    const float* gender_tab = (const float*)d_in[3];
    const float* symp_tab = (const float*)d_in[4];
    const float* Wl1 = (const float*)d_in[5];
    const float* bl1 = (const float*)d_in[6];
    const float* Wr1 = (const float*)d_in[7];
    const float* br1 = (const float*)d_in[8];
    const float* att1 = (const float*)d_in[9];
    const float* bias1 = (const float*)d_in[10];
    const float* Wl2 = (const float*)d_in[11];
    const float* bl2 = (const float*)d_in[12];
    const float* Wr2 = (const float*)d_in[13];
    const float* br2 = (const float*)d_in[14];
    const float* att2 = (const float*)d_in[15];
    const float* bias2 = (const float*)d_in[16];
    const float* linW = (const float*)d_in[17];
    const float* linb = (const float*)d_in[18];
    float* outp = (float*)d_out;

    int N = in_sizes[0] / XCOLS;   // 100000
    int E = in_sizes[1] / 2;       // 1600000

    // workspace partition (256B aligned)
    char* p = (char*)d_ws;
    auto alloc = [&](size_t bytes) {
        void* r = (void*)p;
        p += (bytes + 255) & ~(size_t)255;
        return r;
    };
    float* h0 = (float*)alloc((size_t)N * EMB * 4);
    float* bufA = (float*)alloc((size_t)N * EMB * 4);
    float* bufB = (float*)alloc((size_t)N * EMB * 4);
    int* deg = (int*)alloc((size_t)N * 4);
    int* tmp = (int*)alloc((size_t)N * 4);
    int* offs = (int*)alloc((size_t)(N + 1) * 4);
    int* cursor = (int*)alloc((size_t)N * 4);
    int* bsum = (int*)alloc(4096 * 4);
    int* ssrc = (int*)alloc((size_t)E * 4);

    int nb = (N + 255) / 256;
    int ngrp = (N + 3) / 4;

    // CSR build
    zero_kernel<<<nb, 256, 0, stream>>>(deg, N);
    hist_kernel<<<2048, 256, 0, stream>>>(ei, deg, E);
    scanA_kernel<<<nb, 256, 0, stream>>>(deg, tmp, bsum, N);
    scanB_kernel<<<1, 1024, 0, stream>>>(bsum, nb);
    scanC_kernel<<<nb, 256, 0, stream>>>(tmp, bsum, deg, offs, cursor, N);
    scatter_kernel<<<2048, 256, 0, stream>>>(ei, cursor, ssrc, E);

    // node pipeline
    embed_kernel<<<ngrp, 256, 0, stream>>>(x, birth_tab, gender_tab, symp_tab, h0, N);
    gemm_dual_kernel<<<2048, 256, 0, stream>>>(h0, Wl1, bl1, Wr1, br1, bufA, bufB, N);
    gat_kernel<1><<<ngrp, 256, 0, stream>>>(bufA, bufB, offs, ssrc, att1, bias1,
                                            nullptr, nullptr, h0, N);
    gemm_dual_kernel<<<2048, 256, 0, stream>>>(h0, Wl2, bl2, Wr2, br2, bufA, bufB, N);
    gat_kernel<2><<<ngrp, 256, 0, stream>>>(bufA, bufB, offs, ssrc, att2, bias2,
                                            linW, linb, outp, N);
}

// Round 3
// 546.313 us; speedup vs baseline: 1.4058x; 1.4058x over previous
//
#include <hip/hip_runtime.h>
#include <hip/hip_bf16.h>

#define EMB 64
#define XCOLS 20
#define NSYMP 15

__global__ void zero_kernel(int* __restrict__ p, int n) {
    int i = blockIdx.x * blockDim.x + threadIdx.x;
    if (i < n) p[i] = 0;
}

// ---------------- embedding ----------------
__global__ void embed_kernel(const int* __restrict__ x,
                             const float* __restrict__ bt,
                             const float* __restrict__ gt,
                             const float* __restrict__ st,
                             float* __restrict__ h0, int N) {
    __shared__ int xs[4 * XCOLS];
    int node = blockIdx.x * 4 + (threadIdx.x >> 6);
    int d = threadIdx.x & 63;
    if (threadIdx.x < 4 * XCOLS) {
        int n2 = blockIdx.x * 4 + threadIdx.x / XCOLS;
        int c = threadIdx.x % XCOLS;
        xs[threadIdx.x] = (n2 < N) ? x[n2 * XCOLS + c] : 0;
    }
    __syncthreads();
    if (node >= N) return;
    const int* xr = &xs[(threadIdx.x >> 6) * XCOLS];
    int bi = xr[1] + 2 * xr[2] + 3 * xr[3];   // argmax of one-hot
    int g = xr[4];
    float f = 0.f;
#pragma unroll
    for (int j = 0; j < NSYMP; ++j) {
        int sj = xr[5 + j];
        f += st[(j * 3 + sj) * EMB + d];
    }
    float val = (bt[bi * EMB + d] + gt[g * EMB + d] + f * (1.f / 15.f)) * (1.f / 3.f);
    h0[node * EMB + d] = val;
}

// ---------------- dual GEMM: outL = h@Wl+bl, outR = h@Wr+br (64x64 weights) ----
__global__ void gemm_dual_kernel(const float* __restrict__ h,
                                 const float* __restrict__ Wl, const float* __restrict__ bl,
                                 const float* __restrict__ Wr, const float* __restrict__ br,
                                 float* __restrict__ outL, float* __restrict__ outR, int N) {
    __shared__ float wl[EMB * EMB];
    __shared__ float wr[EMB * EMB];
    __shared__ float hr[2][256];
    for (int i = threadIdx.x; i < EMB * EMB; i += 256) {
        wl[i] = Wl[i];
        wr[i] = Wr[i];
    }
    int ngroups = (N + 3) / 4;
    int r = threadIdx.x >> 6;
    int d = threadIdx.x & 63;
    size_t total = (size_t)N * EMB;
    // preload first tile
    {
        size_t idx = (size_t)blockIdx.x * 256 + threadIdx.x;
        if (blockIdx.x < ngroups) hr[0][threadIdx.x] = (idx < total) ? h[idx] : 0.f;
    }
    int buf = 0;
    for (int g = blockIdx.x; g < ngroups; g += gridDim.x) {
        __syncthreads();                       // hr[buf] (and weights) ready
        int gn = g + gridDim.x;
        if (gn < ngroups) {
            size_t idx = (size_t)gn * 256 + threadIdx.x;
            hr[buf ^ 1][threadIdx.x] = (idx < total) ? h[idx] : 0.f;
        }
        int node = g * 4 + r;
        if (node < N) {
            float al = bl[d], ar = br[d];
#pragma unroll
            for (int k = 0; k < EMB; ++k) {
                float hv = hr[buf][r * EMB + k];
                al += hv * wl[k * EMB + d];
                ar += hv * wr[k * EMB + d];
            }
            outL[node * EMB + d] = al;
            outR[node * EMB + d] = ar;
        }
        buf ^= 1;
    }
}

// ---------------- CSR build (edge_index marshalled as int32) ----------------
__global__ void hist_kernel(const int* __restrict__ ei, int* __restrict__ deg, int E) {
    for (int i = blockIdx.x * blockDim.x + threadIdx.x; i < E; i += gridDim.x * blockDim.x)
        atomicAdd(&deg[ei[E + i]], 1);
}

__global__ void scanA_kernel(const int* __restrict__ deg, int* __restrict__ tmp,
                             int* __restrict__ bsum, int N) {
    __shared__ int s[256];
    int t = threadIdx.x;
    int i = blockIdx.x * 256 + t;
    s[t] = (i < N) ? deg[i] : 0;
    __syncthreads();
    for (int off = 1; off < 256; off <<= 1) {
        int v = (t >= off) ? s[t - off] : 0;
        __syncthreads();
        s[t] += v;
        __syncthreads();
    }
    if (i < N) tmp[i] = s[t];
    if (t == 255) bsum[blockIdx.x] = s[255];
}

__global__ void scanB_kernel(int* __restrict__ bsum, int nb) {
    __shared__ int s[1024];
    int t = threadIdx.x;
    s[t] = (t < nb) ? bsum[t] : 0;
    __syncthreads();
    for (int off = 1; off < 1024; off <<= 1) {
        int v = (t >= off) ? s[t - off] : 0;
        __syncthreads();
        s[t] += v;
        __syncthreads();
    }
    if (t < nb) bsum[t] = s[t];
}

__global__ void scanC_kernel(const int* __restrict__ tmp, const int* __restrict__ bsum,
                             const int* __restrict__ deg, int* __restrict__ offs,
                             int* __restrict__ cursor, int N) {
    int i = blockIdx.x * 256 + threadIdx.x;
    if (i >= N) return;
    int base = (blockIdx.x > 0) ? bsum[blockIdx.x - 1] : 0;
    int incl = tmp[i] + base;
    offs[i + 1] = incl;
    cursor[i] = incl - deg[i];
    if (i == 0) offs[0] = 0;
}

__global__ void scatter_kernel(const int* __restrict__ ei, int* __restrict__ cursor,
                               int* __restrict__ ssrc, int E) {
    for (int i = blockIdx.x * blockDim.x + threadIdx.x; i < E; i += gridDim.x * blockDim.x) {
        int dst = ei[E + i];
        int src = ei[i];
        int p = atomicAdd(&cursor[dst], 1);
        ssrc[p] = src;
    }
}

// ---------------- DPP cross-lane sum helpers (VALU pipe, not LDS) ----------
template <int CTRL>
__device__ __forceinline__ float dpp_add(float v) {
    union { float f; int i; } u, r;
    u.f = v;
    r.i = __builtin_amdgcn_update_dpp(0, u.i, CTRL, 0xF, 0xF, true);
    return v + r.f;
}

// all-reduce sum within each 16-lane group (L=1 head) or all 64 lanes (L=2)
template <int L>
__device__ __forceinline__ float reduce_head(float v) {
    v = dpp_add<0xB1>(v);    // quad_perm [1,0,3,2]  : xor 1
    v = dpp_add<0x4E>(v);    // quad_perm [2,3,0,1]  : xor 2
    v = dpp_add<0x141>(v);   // row_half_mirror      : xor 7 (quad-sums -> 8-sum)
    v = dpp_add<0x140>(v);   // row_mirror           : xor 15 (8-sums -> 16-sum)
    if (L == 2) {
        v += __shfl_xor(v, 16);
        v += __shfl_xor(v, 32);
    }
    return v;
}

// ---------------- GATv2 layer, one wave per destination node ----------------
// L=1: H=4,C=16, output = elu(acc/denom + bias) -> out[n*64+lane]
// L=2: H=1,C=64, output = dot(acc/denom + bias, linW) + linb -> out[n]
template <int L>
__global__ void gat_kernel(const float* __restrict__ xl, const float* __restrict__ xr,
                           const int* __restrict__ offs, const int* __restrict__ ssrc,
                           const float* __restrict__ att, const float* __restrict__ bias,
                           const float* __restrict__ linW, const float* __restrict__ linb,
                           float* __restrict__ out, int N) {
    int wid = blockIdx.x * 4 + (threadIdx.x >> 6);
    int lane = threadIdx.x & 63;
    if (wid >= N) return;

    float att_l = att[lane];
    float xr_l = xr[wid * EMB + lane];
    float bias_l = bias[lane];
    int e0 = offs[wid];
    int e1 = offs[wid + 1];

    // self-loop initializes the online-softmax state
    float x0 = xl[wid * EMB + lane];
    {
    }
    float t0 = x0 + xr_l;
    t0 = (t0 > 0.f) ? t0 : 0.2f * t0;
    float m = reduce_head<L>(att_l * t0);
    float s = 1.f;
    float acc = x0;

    int e = e0;
    // 4-wide unrolled main loop: 4 gathers + 4 logit reductions in flight
    for (; e + 4 <= e1; e += 4) {
        int i0 = ssrc[e], i1 = ssrc[e + 1], i2 = ssrc[e + 2], i3 = ssrc[e + 3];
        float a0 = xl[i0 * EMB + lane];
        float a1 = xl[i1 * EMB + lane];
        float a2 = xl[i2 * EMB + lane];
        float a3 = xl[i3 * EMB + lane];
        float u0 = a0 + xr_l; u0 = (u0 > 0.f) ? u0 : 0.2f * u0;
        float u1 = a1 + xr_l; u1 = (u1 > 0.f) ? u1 : 0.2f * u1;
        float u2 = a2 + xr_l; u2 = (u2 > 0.f) ? u2 : 0.2f * u2;
        float u3 = a3 + xr_l; u3 = (u3 > 0.f) ? u3 : 0.2f * u3;
        float v0 = reduce_head<L>(att_l * u0);
        float v1 = reduce_head<L>(att_l * u1);
        float v2 = reduce_head<L>(att_l * u2);
        float v3 = reduce_head<L>(att_l * u3);
        float nm = fmaxf(fmaxf(m, v0), v1);
        nm = fmaxf(fmaxf(nm, v2), v3);
        float sc = __expf(m - nm);
        float p0 = __expf(v0 - nm);
        float p1 = __expf(v1 - nm);
        float p2 = __expf(v2 - nm);
        float p3 = __expf(v3 - nm);
        s = s * sc + ((p0 + p1) + (p2 + p3));
        acc = acc * sc + ((p0 * a0 + p1 * a1) + (p2 * a2 + p3 * a3));
        m = nm;
    }
    // remainder
    for (; e < e1; ++e) {
        int i0 = ssrc[e];
        float a0 = xl[i0 * EMB + lane];
        float u0 = a0 + xr_l;
        u0 = (u0 > 0.f) ? u0 : 0.2f * u0;
        float v0 = reduce_head<L>(att_l * u0);
        float nm = fmaxf(m, v0);
        float sc = __expf(m - nm);
        float p0 = __expf(v0 - nm);
        s = s * sc + p0;
        acc = acc * sc + p0 * a0;
        m = nm;
    }

    float val = acc / (s + 1e-16f) + bias_l;
    if (L == 1) {
        out[wid * EMB + lane] = (val > 0.f) ? val : (__expf(val) - 1.f);
    } else {
        float r = val * linW[lane];
        r = reduce_head<2>(r);
        if (lane == 0) out[wid] = r + linb[0];
    }
}

extern "C" void kernel_launch(void* const* d_in, const int* in_sizes, int n_in,
                              void* d_out, int out_size, void* d_ws, size_t ws_size,
                              hipStream_t stream) {
    const int* x = (const int*)d_in[0];
    const int* ei = (const int*)d_in[1];          // int32 marshalled
    const float* birth_tab = (const float*)d_in[2];
    const float* gender_tab = (const float*)d_in[3];
    const float* symp_tab = (const float*)d_in[4];
    const float* Wl1 = (const float*)d_in[5];
    const float* bl1 = (const float*)d_in[6];
    const float* Wr1 = (const float*)d_in[7];
    const float* br1 = (const float*)d_in[8];
    const float* att1 = (const float*)d_in[9];
    const float* bias1 = (const float*)d_in[10];
    const float* Wl2 = (const float*)d_in[11];
    const float* bl2 = (const float*)d_in[12];
    const float* Wr2 = (const float*)d_in[13];
    const float* br2 = (const float*)d_in[14];
    const float* att2 = (const float*)d_in[15];
    const float* bias2 = (const float*)d_in[16];
    const float* linW = (const float*)d_in[17];
    const float* linb = (const float*)d_in[18];
    float* outp = (float*)d_out;

    int N = in_sizes[0] / XCOLS;   // 100000
    int E = in_sizes[1] / 2;       // 1600000

    // workspace partition (256B aligned)
    char* p = (char*)d_ws;
    auto alloc = [&](size_t bytes) {
        void* r = (void*)p;
        p += (bytes + 255) & ~(size_t)255;
        return r;
    };
    float* h0 = (float*)alloc((size_t)N * EMB * 4);
    float* bufA = (float*)alloc((size_t)N * EMB * 4);
    float* bufB = (float*)alloc((size_t)N * EMB * 4);
    int* deg = (int*)alloc((size_t)N * 4);
    int* tmp = (int*)alloc((size_t)N * 4);
    int* offs = (int*)alloc((size_t)(N + 1) * 4);
    int* cursor = (int*)alloc((size_t)N * 4);
    int* bsum = (int*)alloc(4096 * 4);
    int* ssrc = (int*)alloc((size_t)E * 4);

    int nb = (N + 255) / 256;
    int ngrp = (N + 3) / 4;

    // CSR build
    zero_kernel<<<nb, 256, 0, stream>>>(deg, N);
    hist_kernel<<<2048, 256, 0, stream>>>(ei, deg, E);
    scanA_kernel<<<nb, 256, 0, stream>>>(deg, tmp, bsum, N);
    scanB_kernel<<<1, 1024, 0, stream>>>(bsum, nb);
    scanC_kernel<<<nb, 256, 0, stream>>>(tmp, bsum, deg, offs, cursor, N);
    scatter_kernel<<<2048, 256, 0, stream>>>(ei, cursor, ssrc, E);

    // node pipeline
    embed_kernel<<<ngrp, 256, 0, stream>>>(x, birth_tab, gender_tab, symp_tab, h0, N);
    gemm_dual_kernel<<<2048, 256, 0, stream>>>(h0, Wl1, bl1, Wr1, br1, bufA, bufB, N);
    gat_kernel<1><<<ngrp, 256, 0, stream>>>(bufA, bufB, offs, ssrc, att1, bias1,
                                            nullptr, nullptr, h0, N);
    gemm_dual_kernel<<<2048, 256, 0, stream>>>(h0, Wl2, bl2, Wr2, br2, bufA, bufB, N);
    gat_kernel<2><<<ngrp, 256, 0, stream>>>(bufA, bufB, offs, ssrc, att2, bias2,
                                            linW, linb, outp, N);
}

// Round 4
// 397.161 us; speedup vs baseline: 1.9338x; 1.3755x over previous
//
#include <hip/hip_runtime.h>
#include <hip/hip_bf16.h>

#define EMB 64
#define XCOLS 20
#define NSYMP 15
#define BSH 7
#define BSZ 128          // nodes per bucket (1<<BSH)
#define MAXNB 1024       // supports N <= 131072
#define PCHUNK 16384

__global__ void zero_kernel(int* __restrict__ p, int n) {
    int i = blockIdx.x * blockDim.x + threadIdx.x;
    if (i < n) p[i] = 0;
}

// ---------------- embedding ----------------
__global__ void embed_kernel(const int* __restrict__ x,
                             const float* __restrict__ bt,
                             const float* __restrict__ gt,
                             const float* __restrict__ st,
                             float* __restrict__ h0, int N) {
    __shared__ int xs[4 * XCOLS];
    int node = blockIdx.x * 4 + (threadIdx.x >> 6);
    int d = threadIdx.x & 63;
    if (threadIdx.x < 4 * XCOLS) {
        int n2 = blockIdx.x * 4 + threadIdx.x / XCOLS;
        int c = threadIdx.x % XCOLS;
        xs[threadIdx.x] = (n2 < N) ? x[n2 * XCOLS + c] : 0;
    }
    __syncthreads();
    if (node >= N) return;
    const int* xr = &xs[(threadIdx.x >> 6) * XCOLS];
    int bi = xr[1] + 2 * xr[2] + 3 * xr[3];   // argmax of one-hot
    int g = xr[4];
    float f = 0.f;
#pragma unroll
    for (int j = 0; j < NSYMP; ++j) {
        int sj = xr[5 + j];
        f += st[(j * 3 + sj) * EMB + d];
    }
    float val = (bt[bi * EMB + d] + gt[g * EMB + d] + f * (1.f / 15.f)) * (1.f / 3.f);
    h0[node * EMB + d] = val;
}

// ---------------- dual GEMM: outL = h@Wl+bl, outR = h@Wr+br (64x64 weights) ----
__global__ void gemm_dual_kernel(const float* __restrict__ h,
                                 const float* __restrict__ Wl, const float* __restrict__ bl,
                                 const float* __restrict__ Wr, const float* __restrict__ br,
                                 float* __restrict__ outL, float* __restrict__ outR, int N) {
    __shared__ float wl[EMB * EMB];
    __shared__ float wr[EMB * EMB];
    __shared__ float hr[2][256];
    for (int i = threadIdx.x; i < EMB * EMB; i += 256) {
        wl[i] = Wl[i];
        wr[i] = Wr[i];
    }
    int ngroups = (N + 3) / 4;
    int r = threadIdx.x >> 6;
    int d = threadIdx.x & 63;
    size_t total = (size_t)N * EMB;
    {
        size_t idx = (size_t)blockIdx.x * 256 + threadIdx.x;
        if (blockIdx.x < ngroups) hr[0][threadIdx.x] = (idx < total) ? h[idx] : 0.f;
    }
    int buf = 0;
    for (int g = blockIdx.x; g < ngroups; g += gridDim.x) {
        __syncthreads();
        int gn = g + gridDim.x;
        if (gn < ngroups) {
            size_t idx = (size_t)gn * 256 + threadIdx.x;
            hr[buf ^ 1][threadIdx.x] = (idx < total) ? h[idx] : 0.f;
        }
        int node = g * 4 + r;
        if (node < N) {
            float al = bl[d], ar = br[d];
#pragma unroll
            for (int k = 0; k < EMB; ++k) {
                float hv = hr[buf][r * EMB + k];
                al += hv * wl[k * EMB + d];
                ar += hv * wr[k * EMB + d];
            }
            outL[node * EMB + d] = al;
            outR[node * EMB + d] = ar;
        }
        buf ^= 1;
    }
}

// ---------------- CSR build via 2-level radix partition ----------------
// K1: per-bucket counts (LDS histogram, merged once per WG)
__global__ void bincount_kernel(const int* __restrict__ ei, int* __restrict__ bcount,
                                int* __restrict__ offs, int E, int NB, int N) {
    __shared__ int lh[MAXNB];
    for (int j = threadIdx.x; j < NB; j += 256) lh[j] = 0;
    __syncthreads();
    for (int i = blockIdx.x * 256 + threadIdx.x; i < E; i += gridDim.x * 256)
        atomicAdd(&lh[ei[E + i] >> BSH], 1);
    __syncthreads();
    for (int j = threadIdx.x; j < NB; j += 256)
        if (lh[j]) atomicAdd(&bcount[j], lh[j]);
    if (blockIdx.x == 0 && threadIdx.x == 0) offs[N] = E;
}

// K2: scan bucket counts (NB <= 1024, one workgroup)
__global__ void bscan_kernel(const int* __restrict__ bcount, int* __restrict__ boffs,
                             int* __restrict__ bcursor, int NB) {
    __shared__ int s[1024];
    int t = threadIdx.x;
    int v0 = (t < NB) ? bcount[t] : 0;
    s[t] = v0;
    __syncthreads();
    for (int off = 1; off < 1024; off <<= 1) {
        int v = (t >= off) ? s[t - off] : 0;
        __syncthreads();
        s[t] += v;
        __syncthreads();
    }
    if (t < NB) {
        boffs[t + 1] = s[t];
        bcursor[t] = s[t] - v0;
    }
    if (t == 0) boffs[0] = 0;
}

// K3: partition edges into bucket-major order, packed (src<<BSH)|dst_local.
// Per-WG contiguous runs per bucket -> coalesced, XCD-private write lines.
__global__ void partition_kernel(const int* __restrict__ ei, int* __restrict__ bcursor,
                                 int* __restrict__ epart, int E, int NB) {
    __shared__ int lh[MAXNB];
    for (int j = threadIdx.x; j < NB; j += 256) lh[j] = 0;
    __syncthreads();
    int base = blockIdx.x * PCHUNK;
    int end = min(E, base + PCHUNK);
    for (int i = base + threadIdx.x; i < end; i += 256)
        atomicAdd(&lh[ei[E + i] >> BSH], 1);
    __syncthreads();
    for (int j = threadIdx.x; j < NB; j += 256) {
        int c = lh[j];
        lh[j] = c ? atomicAdd(&bcursor[j], c) : 0;
    }
    __syncthreads();
    for (int i = base + threadIdx.x; i < end; i += 256) {
        int dst = ei[E + i];
        int src = ei[i];
        int slot = atomicAdd(&lh[dst >> BSH], 1);
        epart[slot] = (src << BSH) | (dst & (BSZ - 1));
    }
}

// K4: within each bucket (contiguous 8KB window), build fine CSR with LDS
// deg/scan/cursor. Writes offs + dst-sorted ssrc.
__global__ void finalize_kernel(const int* __restrict__ epart, const int* __restrict__ boffs,
                                int* __restrict__ offs, int* __restrict__ ssrc, int N) {
    __shared__ int deg[BSZ], pos[BSZ], cur[BSZ];
    int b = blockIdx.x;
    int t = threadIdx.x;
    int n0 = b << BSH;
    int r0 = boffs[b], r1 = boffs[b + 1];
    if (t < BSZ) deg[t] = 0;
    __syncthreads();
    for (int e = r0 + t; e < r1; e += 256)
        atomicAdd(&deg[epart[e] & (BSZ - 1)], 1);
    __syncthreads();
    if (t < BSZ) pos[t] = deg[t];
    __syncthreads();
    for (int off = 1; off < BSZ; off <<= 1) {
        int v = (t < BSZ && t >= off) ? pos[t - off] : 0;
        __syncthreads();
        if (t < BSZ) pos[t] += v;
        __syncthreads();
    }
    if (t < BSZ) {
        int ex = r0 + pos[t] - deg[t];
        cur[t] = ex;
        int node = n0 + t;
        if (node < N) offs[node] = ex;
    }
    __syncthreads();
    for (int e = r0 + t; e < r1; e += 256) {
        int v = epart[e];
        int s = atomicAdd(&cur[v & (BSZ - 1)], 1);
        ssrc[s] = v >> BSH;
    }
}

// ---------------- DPP cross-lane sum helpers (VALU pipe, not LDS) ----------
template <int CTRL>
__device__ __forceinline__ float dpp_add(float v) {
    union { float f; int i; } u, r;
    u.f = v;
    r.i = __builtin_amdgcn_update_dpp(0, u.i, CTRL, 0xF, 0xF, true);
    return v + r.f;
}

template <int L>
__device__ __forceinline__ float reduce_head(float v) {
    v = dpp_add<0xB1>(v);    // quad_perm xor1
    v = dpp_add<0x4E>(v);    // quad_perm xor2
    v = dpp_add<0x141>(v);   // row_half_mirror
    v = dpp_add<0x140>(v);   // row_mirror -> 16-lane sum
    if (L == 2) {
        v += __shfl_xor(v, 16);
        v += __shfl_xor(v, 32);
    }
    return v;
}

// ---------------- GATv2 layer, one wave per destination node ----------------
template <int L>
__global__ void gat_kernel(const float* __restrict__ xl, const float* __restrict__ xr,
                           const int* __restrict__ offs, const int* __restrict__ ssrc,
                           const float* __restrict__ att, const float* __restrict__ bias,
                           const float* __restrict__ linW, const float* __restrict__ linb,
                           float* __restrict__ out, int N) {
    int wid = blockIdx.x * 4 + (threadIdx.x >> 6);
    int lane = threadIdx.x & 63;
    if (wid >= N) return;

    float att_l = att[lane];
    float xr_l = xr[wid * EMB + lane];
    float bias_l = bias[lane];
    int e0 = offs[wid];
    int e1 = offs[wid + 1];

    // self-loop initializes the online-softmax state
    float x0 = xl[wid * EMB + lane];
    float t0 = x0 + xr_l;
    t0 = (t0 > 0.f) ? t0 : 0.2f * t0;
    float m = reduce_head<L>(att_l * t0);
    float s = 1.f;
    float acc = x0;

    int e = e0;
    for (; e + 4 <= e1; e += 4) {
        int i0 = ssrc[e], i1 = ssrc[e + 1], i2 = ssrc[e + 2], i3 = ssrc[e + 3];
        float a0 = xl[i0 * EMB + lane];
        float a1 = xl[i1 * EMB + lane];
        float a2 = xl[i2 * EMB + lane];
        float a3 = xl[i3 * EMB + lane];
        float u0 = a0 + xr_l; u0 = (u0 > 0.f) ? u0 : 0.2f * u0;
        float u1 = a1 + xr_l; u1 = (u1 > 0.f) ? u1 : 0.2f * u1;
        float u2 = a2 + xr_l; u2 = (u2 > 0.f) ? u2 : 0.2f * u2;
        float u3 = a3 + xr_l; u3 = (u3 > 0.f) ? u3 : 0.2f * u3;
        float v0 = reduce_head<L>(att_l * u0);
        float v1 = reduce_head<L>(att_l * u1);
        float v2 = reduce_head<L>(att_l * u2);
        float v3 = reduce_head<L>(att_l * u3);
        float nm = fmaxf(fmaxf(m, v0), v1);
        nm = fmaxf(fmaxf(nm, v2), v3);
        float sc = __expf(m - nm);
        float p0 = __expf(v0 - nm);
        float p1 = __expf(v1 - nm);
        float p2 = __expf(v2 - nm);
        float p3 = __expf(v3 - nm);
        s = s * sc + ((p0 + p1) + (p2 + p3));
        acc = acc * sc + ((p0 * a0 + p1 * a1) + (p2 * a2 + p3 * a3));
        m = nm;
    }
    for (; e < e1; ++e) {
        int i0 = ssrc[e];
        float a0 = xl[i0 * EMB + lane];
        float u0 = a0 + xr_l;
        u0 = (u0 > 0.f) ? u0 : 0.2f * u0;
        float v0 = reduce_head<L>(att_l * u0);
        float nm = fmaxf(m, v0);
        float sc = __expf(m - nm);
        float p0 = __expf(v0 - nm);
        s = s * sc + p0;
        acc = acc * sc + p0 * a0;
        m = nm;
    }

    float val = acc / (s + 1e-16f) + bias_l;
    if (L == 1) {
        out[wid * EMB + lane] = (val > 0.f) ? val : (__expf(val) - 1.f);
    } else {
        float r = val * linW[lane];
        r = reduce_head<2>(r);
        if (lane == 0) out[wid] = r + linb[0];
    }
}

extern "C" void kernel_launch(void* const* d_in, const int* in_sizes, int n_in,
                              void* d_out, int out_size, void* d_ws, size_t ws_size,
                              hipStream_t stream) {
    const int* x = (const int*)d_in[0];
    const int* ei = (const int*)d_in[1];          // int32 marshalled
    const float* birth_tab = (const float*)d_in[2];
    const float* gender_tab = (const float*)d_in[3];
    const float* symp_tab = (const float*)d_in[4];
    const float* Wl1 = (const float*)d_in[5];
    const float* bl1 = (const float*)d_in[6];
    const float* Wr1 = (const float*)d_in[7];
    const float* br1 = (const float*)d_in[8];
    const float* att1 = (const float*)d_in[9];
    const float* bias1 = (const float*)d_in[10];
    const float* Wl2 = (const float*)d_in[11];
    const float* bl2 = (const float*)d_in[12];
    const float* Wr2 = (const float*)d_in[13];
    const float* br2 = (const float*)d_in[14];
    const float* att2 = (const float*)d_in[15];
    const float* bias2 = (const float*)d_in[16];
    const float* linW = (const float*)d_in[17];
    const float* linb = (const float*)d_in[18];
    float* outp = (float*)d_out;

    int N = in_sizes[0] / XCOLS;   // 100000
    int E = in_sizes[1] / 2;       // 1600000
    int NB = (N + BSZ - 1) >> BSH; // 782

    // workspace partition (256B aligned)
    char* p = (char*)d_ws;
    auto alloc = [&](size_t bytes) {
        void* r = (void*)p;
        p += (bytes + 255) & ~(size_t)255;
        return r;
    };
    float* h0 = (float*)alloc((size_t)N * EMB * 4);
    float* bufA = (float*)alloc((size_t)N * EMB * 4);
    float* bufB = (float*)alloc((size_t)N * EMB * 4);
    int* bcount = (int*)alloc(MAXNB * 4);
    int* boffs = (int*)alloc((MAXNB + 1) * 4);
    int* bcursor = (int*)alloc(MAXNB * 4);
    int* offs = (int*)alloc((size_t)(N + 1) * 4);
    int* epart = (int*)alloc((size_t)E * 4);
    int* ssrc = (int*)alloc((size_t)E * 4);

    int ngrp = (N + 3) / 4;

    // CSR build (2-level radix partition)
    zero_kernel<<<(NB + 255) / 256, 256, 0, stream>>>(bcount, NB);
    bincount_kernel<<<256, 256, 0, stream>>>(ei, bcount, offs, E, NB, N);
    bscan_kernel<<<1, 1024, 0, stream>>>(bcount, boffs, bcursor, NB);
    partition_kernel<<<(E + PCHUNK - 1) / PCHUNK, 256, 0, stream>>>(ei, bcursor, epart, E, NB);
    finalize_kernel<<<NB, 256, 0, stream>>>(epart, boffs, offs, ssrc, N);

    // node pipeline
    embed_kernel<<<ngrp, 256, 0, stream>>>(x, birth_tab, gender_tab, symp_tab, h0, N);
    gemm_dual_kernel<<<2048, 256, 0, stream>>>(h0, Wl1, bl1, Wr1, br1, bufA, bufB, N);
    gat_kernel<1><<<ngrp, 256, 0, stream>>>(bufA, bufB, offs, ssrc, att1, bias1,
                                            nullptr, nullptr, h0, N);
    gemm_dual_kernel<<<2048, 256, 0, stream>>>(h0, Wl2, bl2, Wr2, br2, bufA, bufB, N);
    gat_kernel<2><<<ngrp, 256, 0, stream>>>(bufA, bufB, offs, ssrc, att2, bias2,
                                            linW, linb, outp, N);
}